// Round 5
// baseline (352.956 us; speedup 1.0000x reference)
//
#include <hip/hip_runtime.h>
#include <cstdint>
#include <cstddef>

typedef __bf16 bf16;
typedef __bf16 bf16x8 __attribute__((ext_vector_type(8)));
typedef float  f32x4 __attribute__((ext_vector_type(4)));

#define MFMA16(a, b, c) __builtin_amdgcn_mfma_f32_16x16x32_bf16((a), (b), (c), 0, 0, 0)
#define MFMA16F8(a, b, c) __builtin_amdgcn_mfma_f32_16x16x32_fp8_fp8((a), (b), (c), 0, 0, 0)

// float -> fp8 e4m3 (OCP), RNE, single byte
__device__ __forceinline__ uint8_t to_fp8(float v) {
    return (uint8_t)(__builtin_amdgcn_cvt_pk_fp8_f32(v, v, 0, false) & 0xff);
}

// async global->LDS, 16B per lane. LDS dest is wave-uniform base + lane*16,
// which all call sites guarantee (ci = i*256 + tid).
__device__ __forceinline__ void gload16(const void* g, void* l) {
    __builtin_amdgcn_global_load_lds(
        (const __attribute__((address_space(1))) unsigned int*)g,
        (__attribute__((address_space(3))) unsigned int*)l,
        16, 0, 0);
}

// ---------------------------------------------------------------------------
// Weight fp32 -> bf16 convert (w_qkv 1152x384, w_proj 384x384)
// ---------------------------------------------------------------------------
__global__ __launch_bounds__(256) void convert_w(
    const float* __restrict__ wqkv, const float* __restrict__ wproj,
    bf16* __restrict__ wq, bf16* __restrict__ wp)
{
    int t = blockIdx.x * 256 + threadIdx.x;      // grid covers 589824
    if (t < 1152 * 384) wq[t] = (bf16)wqkv[t];
    else                wp[t - 1152 * 384] = (bf16)wproj[t - 1152 * 384];
}

// ---------------------------------------------------------------------------
// RMSNorm over channel dim, x [4][384][4096] fp32 -> xn [16384][384] bf16
// ---------------------------------------------------------------------------
__global__ __launch_bounds__(64) void norm_kernel(
    const float* __restrict__ x, const float* __restrict__ gamma,
    bf16* __restrict__ xn)
{
    __shared__ float sG[384];
    int tid = threadIdx.x;
    for (int i = tid; i < 384; i += 64) sG[i] = gamma[i];
    __syncthreads();
    int t = blockIdx.x * 64 + tid;               // 0..16383 (one pixel)
    int b = t >> 12, p = t & 4095;
    const float* xb = x + (size_t)(b * 384) * 4096 + p;
    float ss = 0.f;
    for (int c = 0; c < 384; ++c) { float v = xb[(size_t)c * 4096]; ss += v * v; }
    float scale = 19.595917942265423f / fmaxf(sqrtf(ss), 1e-12f); // sqrt(384)/max(l2,eps)
    bf16* o = xn + (size_t)t * 384;
    for (int c0 = 0; c0 < 384; c0 += 8) {
        bf16x8 v8;
#pragma unroll
        for (int j = 0; j < 8; ++j)
            v8[j] = (bf16)(xb[(size_t)(c0 + j) * 4096] * scale * sG[c0 + j]);
        *(bf16x8*)(o + c0) = v8;
    }
}

// ---------------------------------------------------------------------------
// Generic BT GEMM: C[m][n] = sum_k A[m][k]*B[n][k], K=384 fixed, tiles 128x128.
// mode 0: C fp8 = acc + bias_n[n],  ldc given        (QK -> qkb buffer)
// mode 1: C fp8 = acc + bias_m[m],  ldc given        (V^T buffer)
// mode 2: C fp32 out[(b*384+m)*4096+p] = acc + bias_m[m] + resid[idx], n=b*4096+p
// ---------------------------------------------------------------------------
__global__ __launch_bounds__(256) void gemm_bt(
    const bf16* __restrict__ A, const bf16* __restrict__ B,
    const float* __restrict__ bias_m, const float* __restrict__ bias_n,
    const float* __restrict__ resid, void* __restrict__ Cout,
    int mode, int ldc)
{
    __shared__ bf16 sA[128 * 72];   // 144B rows (128B data + 16B pad)
    __shared__ bf16 sB[128 * 72];
    const int tid = threadIdx.x;
    const int l = tid & 63, w = tid >> 6;
    const int lo = l & 15, hi = l >> 4;
    const int wm = w >> 1, wn = w & 1;
    const int m0 = blockIdx.y * 128, n0 = blockIdx.x * 128;

    f32x4 acc[4][4] = {};

    for (int kt = 0; kt < 6; ++kt) {
        __syncthreads();
        const int k0 = kt * 64;
#pragma unroll
        for (int i = 0; i < 5; ++i) {
            int ci = i * 256 + tid;              // 1152 chunks of 16B per tile
            if (ci < 1152) {
                int row = ci / 9, off = ci % 9;  // off==8 loads harmless slack into pad
                gload16(A + (size_t)(m0 + row) * 384 + k0 + off * 8, (char*)sA + ci * 16);
                gload16(B + (size_t)(n0 + row) * 384 + k0 + off * 8, (char*)sB + ci * 16);
            }
        }
        __syncthreads();
#pragma unroll
        for (int ks = 0; ks < 2; ++ks) {
            bf16x8 af[4], bfr[4];
#pragma unroll
            for (int t = 0; t < 4; ++t)
                af[t] = *(const bf16x8*)(sA + (wm * 64 + t * 16 + lo) * 72 + ks * 32 + hi * 8);
#pragma unroll
            for (int t = 0; t < 4; ++t)
                bfr[t] = *(const bf16x8*)(sB + (wn * 64 + t * 16 + lo) * 72 + ks * 32 + hi * 8);
#pragma unroll
            for (int rt = 0; rt < 4; ++rt)
#pragma unroll
                for (int ct = 0; ct < 4; ++ct)
                    acc[rt][ct] = MFMA16(af[rt], bfr[ct], acc[rt][ct]);
        }
    }

    // epilogue: C/D layout col = lo, row = hi*4 + reg
#pragma unroll
    for (int rt = 0; rt < 4; ++rt) {
#pragma unroll
        for (int ct = 0; ct < 4; ++ct) {
            int mb = m0 + wm * 64 + rt * 16 + hi * 4;
            int n  = n0 + wn * 64 + ct * 16 + lo;
            if (mode == 0) {
                uint8_t* C = (uint8_t*)Cout;
                float bn = bias_n[n];
#pragma unroll
                for (int r = 0; r < 4; ++r)
                    C[(size_t)(mb + r) * ldc + n] = to_fp8(acc[rt][ct][r] + bn);
            } else if (mode == 1) {
                uint8_t* C = (uint8_t*)Cout;
#pragma unroll
                for (int r = 0; r < 4; ++r)
                    C[(size_t)(mb + r) * ldc + n] = to_fp8(acc[rt][ct][r] + bias_m[mb + r]);
            } else {
                float* O = (float*)Cout;
                int bb = n >> 12, p = n & 4095;
#pragma unroll
                for (int r = 0; r < 4; ++r) {
                    int m = mb + r;
                    size_t idx = ((size_t)(bb * 384 + m)) * 4096 + p;
                    O[idx] = acc[rt][ct][r] + bias_m[m] + resid[idx];
                }
            }
        }
    }
}

// ---------------------------------------------------------------------------
// Flash attention, transposed-S, fp8, 16x16x32 MFMA, double-buffered LDS.
// qk [16384][768] fp8 (Q|K), vt [384][16384] fp8 (V^T).
// Grid (64 qtiles, b*2+half). Block 256 = 4 waves (wq = q-half, wd = d-half).
// Lane coords (lo = l&15, h = l>>4). S^T tiles [16kv][16q] = K·Q^T with
// kv in regs, q in lanes; per-lane online softmax (raw-score domain, SC
// folded into exp2); P^T -> PV B-frags via 8 shfl; O^T[192d][32q] += V^T·P^T.
// One barrier per k-iter: next tile's DMA issued before compute on current.
// Partials (unnormalized O bf16 + m*SC,l) merged by merge_kernel.
// Double buffer layout: buf b at smem + b*31232 (K 12800 B, then V^T 18432 B).
// ---------------------------------------------------------------------------
__device__ __forceinline__ void stage_tiles(
    const uint8_t* __restrict__ qk, const uint8_t* __restrict__ vt,
    int kv0, uint8_t* sK, uint8_t* sVT, int tid)
{
    const uint8_t* kb = qk + (size_t)kv0 * 768 + 384;
#pragma unroll
    for (int i = 0; i < 4; ++i) {
        int ci = i * 256 + tid;
        if (ci < 800) {                        // 32 rows * 25 chunks (24 data + 1 pad)
            int row = ci / 25, off = ci % 25;
            gload16(kb + (size_t)row * 768 + off * 16, sK + ci * 16);
        }
    }
    const uint8_t* vb = vt + kv0;
#pragma unroll
    for (int i = 0; i < 5; ++i) {
        int ci = i * 256 + tid;
        if (ci < 1152) {                       // 384 rows * 3 chunks (2 data + 1 pad)
            int row = ci / 3, off = ci % 3;
            gload16(vb + (size_t)row * 16384 + off * 16, sVT + ci * 16);
        }
    }
}

__global__ __launch_bounds__(256, 2) void flash_kernel(
    const uint8_t* __restrict__ qk, const uint8_t* __restrict__ vt,
    bf16* __restrict__ op0, bf16* __restrict__ op1, float* __restrict__ ml)
{
    __shared__ char smem[62464];               // 2 x (12800 K + 18432 V^T)
    const int tid = threadIdx.x;
    const int l = tid & 63, w = tid >> 6;
    const int lo = l & 15, h = l >> 4;         // MFMA16 lane coords
    const int l31 = l & 31, hi2 = l >> 5;      // epilogue coords
    const int wq = w >> 1, wd = w & 1;
    const int qt = blockIdx.x, bh = blockIdx.y;
    const int b = bh >> 1, half = bh & 1;
    const int q0 = b * 4096 + qt * 64;
    const int kvbase = b * 4096 + half * 2048;
    const float SC = 0.07362217057594547f;     // (1/sqrt(384)) * log2(e)

    // Q B-frags: lane holds Q[q0+wq*32+q2*16+lo][ksw*32 + h*8 + j], j=0..7
    long qf[2][12];
#pragma unroll
    for (int q2 = 0; q2 < 2; ++q2) {
        const uint8_t* qrow = qk + (size_t)(q0 + wq * 32 + q2 * 16 + lo) * 768;
#pragma unroll
        for (int ksw = 0; ksw < 12; ++ksw)
            qf[q2][ksw] = *(const long*)(qrow + ksw * 32 + h * 8);
    }

    f32x4 o[12][2] = {};                        // [dt][q2]; d = dt*16+h*4+r, q = q2*16+lo
    float m[2] = {-1e30f, -1e30f}, lsum[2] = {0.f, 0.f};

    stage_tiles(qk, vt, kvbase, (uint8_t*)smem, (uint8_t*)smem + 12800, tid);
    __syncthreads();                            // compiler drains vmcnt before barrier

    for (int kt = 0; kt < 64; ++kt) {
        uint8_t* cbase = (uint8_t*)smem + (kt & 1) * 31232;
        uint8_t* nbase = (uint8_t*)smem + ((kt & 1) ^ 1) * 31232;
        if (kt < 63)
            stage_tiles(qk, vt, kvbase + (kt + 1) * 32, nbase, nbase + 12800, tid);
        const uint8_t* K = cbase;
        const uint8_t* V = cbase + 12800;

        // S^T tiles [kvt][q2]: A = K rows (m=kv), B = Q regs (n=q)
        f32x4 s[2][2] = {};
#pragma unroll
        for (int ksw = 0; ksw < 12; ++ksw) {
            long ak0 = *(const long*)(K + (size_t)lo * 400 + ksw * 32 + h * 8);
            long ak1 = *(const long*)(K + (size_t)(16 + lo) * 400 + ksw * 32 + h * 8);
            s[0][0] = MFMA16F8(ak0, qf[0][ksw], s[0][0]);
            s[0][1] = MFMA16F8(ak0, qf[1][ksw], s[0][1]);
            s[1][0] = MFMA16F8(ak1, qf[0][ksw], s[1][0]);
            s[1][1] = MFMA16F8(ak1, qf[1][ksw], s[1][1]);
        }

        // online softmax: lane holds kv = kvt*16+h*4+r for q = q2*16+lo
        float mx[2];
#pragma unroll
        for (int q2 = 0; q2 < 2; ++q2) {
            float t = fmaxf(fmaxf(fmaxf(s[0][q2][0], s[0][q2][1]),
                                  fmaxf(s[0][q2][2], s[0][q2][3])),
                            fmaxf(fmaxf(s[1][q2][0], s[1][q2][1]),
                                  fmaxf(s[1][q2][2], s[1][q2][3])));
            t = fmaxf(t, __shfl_xor(t, 16));
            t = fmaxf(t, __shfl_xor(t, 32));
            mx[q2] = t;
        }
        if (__any(mx[0] > m[0] || mx[1] > m[1])) {   // rare after warmup
            float alpha[2];
#pragma unroll
            for (int q2 = 0; q2 < 2; ++q2) {
                float mn = fmaxf(m[q2], mx[q2]);
                alpha[q2] = exp2f((m[q2] - mn) * SC);
                m[q2] = mn;
                lsum[q2] *= alpha[q2];
            }
#pragma unroll
            for (int dt = 0; dt < 12; ++dt)
#pragma unroll
                for (int q2 = 0; q2 < 2; ++q2)
#pragma unroll
                    for (int r = 0; r < 4; ++r) o[dt][q2][r] *= alpha[q2];
        }
        float p[2][2][4];
#pragma unroll
        for (int q2 = 0; q2 < 2; ++q2) {
            float msc = m[q2] * SC;
            float rs = 0.f;
#pragma unroll
            for (int kvt = 0; kvt < 2; ++kvt)
#pragma unroll
                for (int r = 0; r < 4; ++r) {
                    float pv = exp2f(fmaf(s[kvt][q2][r], SC, -msc));
                    p[kvt][q2][r] = pv;
                    rs += pv;
                }
            rs += __shfl_xor(rs, 16);
            rs += __shfl_xor(rs, 32);
            lsum[q2] += rs;
        }

        // pack P into fp8 dwords (4 kv each), build PV B-frags via shfl.
        // provider (lo,h): pk[kvt][q2] = kv {kvt*16+h*4 .. +3} of q=q2*16+lo.
        // requester (lo,h) needs kv {h*8..h*8+7}: dword0 from lane lo+((h&1)<<5),
        // dword1 from +16, selecting pk[h>>1].
        int pk[2][2];
#pragma unroll
        for (int kvt = 0; kvt < 2; ++kvt)
#pragma unroll
            for (int q2 = 0; q2 < 2; ++q2) {
                int d = __builtin_amdgcn_cvt_pk_fp8_f32(p[kvt][q2][0], p[kvt][q2][1], 0, false);
                d     = __builtin_amdgcn_cvt_pk_fp8_f32(p[kvt][q2][2], p[kvt][q2][3], d, true);
                pk[kvt][q2] = d;
            }
        const int src1 = lo + ((h & 1) << 5);
        const int src2 = src1 + 16;
        const bool kvhi = (h >> 1) != 0;
        long pfrag[2];
#pragma unroll
        for (int q2 = 0; q2 < 2; ++q2) {
            int a0 = __shfl(pk[0][q2], src1), b0 = __shfl(pk[1][q2], src1);
            int a1 = __shfl(pk[0][q2], src2), b1 = __shfl(pk[1][q2], src2);
            int dw[2];
            dw[0] = kvhi ? b0 : a0;
            dw[1] = kvhi ? b1 : a1;
            pfrag[q2] = *(long*)dw;
        }

        // O^T[d][q] += V^T · P^T  (A: V^T rows m=d, k=kv = h*8+j)
#pragma unroll
        for (int dt = 0; dt < 12; ++dt) {
            long av = *(const long*)(V + (size_t)(wd * 192 + dt * 16 + lo) * 48 + h * 8);
            o[dt][0] = MFMA16F8(av, pfrag[0], o[dt][0]);
            o[dt][1] = MFMA16F8(av, pfrag[1], o[dt][1]);
        }

        __syncthreads();   // all waves done with cur; next tile's DMA drained
    }

    // epilogue: per-wave O^T -> O transpose through LDS (reuse tile space)
    float* tr = (float*)(smem + w * 2560);       // [32 q][20 pitch] fp32
    bf16* dst = half ? op1 : op0;
#pragma unroll
    for (int dt = 0; dt < 12; ++dt) {
#pragma unroll
        for (int q2 = 0; q2 < 2; ++q2)
#pragma unroll
            for (int r = 0; r < 4; ++r)
                tr[(q2 * 16 + lo) * 20 + h * 4 + r] = o[dt][q2][r];
        // lane reads q=l31, d-half hi2 (wave-synchronous: same-wave write->read)
        f32x4 v0 = *(f32x4*)(tr + l31 * 20 + hi2 * 8 + 0);
        f32x4 v1 = *(f32x4*)(tr + l31 * 20 + hi2 * 8 + 4);
        bf16x8 hv;
#pragma unroll
        for (int j = 0; j < 4; ++j) { hv[j] = (bf16)v0[j]; hv[4 + j] = (bf16)v1[j]; }
        size_t tok = (size_t)(q0 + wq * 32 + l31);
        *(bf16x8*)(dst + tok * 384 + wd * 192 + dt * 16 + hi2 * 8) = hv;
    }
    if (wd == 0 && h == 0) {
#pragma unroll
        for (int q2 = 0; q2 < 2; ++q2) {
            int tok = q0 + wq * 32 + q2 * 16 + lo;
            ml[(size_t)(half * 16384 + tok) * 2 + 0] = m[q2] * SC;   // scaled domain
            ml[(size_t)(half * 16384 + tok) * 2 + 1] = lsum[q2];
        }
    }
}

// ---------------------------------------------------------------------------
// Merge the two kv-half partials: out = (a0*O0 + a1*O1) / (a0*l0 + a1*l1).
// One wave per token; p1 aliases ob (in-place safe, element-wise).
// ---------------------------------------------------------------------------
__global__ __launch_bounds__(256) void merge_kernel(
    const bf16* __restrict__ p0, const bf16* __restrict__ p1,
    const float* __restrict__ ml, bf16* __restrict__ ob)
{
    int tok = blockIdx.x * 4 + (threadIdx.x >> 6);
    int l = threadIdx.x & 63;
    float m0 = ml[(size_t)tok * 2 + 0], l0 = ml[(size_t)tok * 2 + 1];
    float m1 = ml[(size_t)(16384 + tok) * 2 + 0], l1 = ml[(size_t)(16384 + tok) * 2 + 1];
    float mM = fmaxf(m0, m1);
    float a0 = exp2f(m0 - mM), a1 = exp2f(m1 - mM);
    float inv = 1.0f / (a0 * l0 + a1 * l1);
    float w0 = a0 * inv, w1 = a1 * inv;
    if (l < 48) {
        size_t off = (size_t)tok * 384 + l * 8;
        bf16x8 v0 = *(const bf16x8*)(p0 + off);
        bf16x8 v1 = *(const bf16x8*)(p1 + off);
        bf16x8 r;
#pragma unroll
        for (int j = 0; j < 8; ++j)
            r[j] = (bf16)((float)v0[j] * w0 + (float)v1[j] * w1);
        *(bf16x8*)(ob + off) = r;
    }
}

// ---------------------------------------------------------------------------
extern "C" void kernel_launch(void* const* d_in, const int* in_sizes, int n_in,
                              void* d_out, int out_size, void* d_ws, size_t ws_size,
                              hipStream_t stream) {
    const float* x      = (const float*)d_in[0];
    const float* gamma  = (const float*)d_in[1];
    const float* w_qkv  = (const float*)d_in[2];
    const float* b_qkv  = (const float*)d_in[3];
    const float* w_proj = (const float*)d_in[4];
    const float* b_proj = (const float*)d_in[5];
    float* out = (float*)d_out;

    // workspace carve (~46 MiB); staging 16B overreads at buffer tails land
    // in the next ws buffer. xn is dead after the two gemms -> reused as op0.
    char* ws = (char*)d_ws;
    bf16* xn  = (bf16*)ws;    ws += (size_t)16384 * 384 * 2;   // normalized x / flash partial-0
    uint8_t* qkb = (uint8_t*)ws; ws += (size_t)16384 * 768;    // Q|K fp8, [tok][768]
    uint8_t* vtb = (uint8_t*)ws; ws += (size_t)384 * 16384;    // V^T fp8, [d][tok]
    bf16* ob  = (bf16*)ws;    ws += (size_t)16384 * 384 * 2;   // flash partial-1 / merged attn out
    bf16* wq  = (bf16*)ws;    ws += (size_t)1152 * 384 * 2;    // w_qkv bf16
    bf16* wp  = (bf16*)ws;    ws += (size_t)384 * 384 * 2;     // w_proj bf16
    float* mlb = (float*)ws;  ws += (size_t)2 * 16384 * 2 * 4; // m*SC,l per (half, tok)

    convert_w<<<2304, 256, 0, stream>>>(w_qkv, w_proj, wq, wp);
    norm_kernel<<<256, 64, 0, stream>>>(x, gamma, xn);
    // QK fp8: C[tok][o] = xn @ w_qk^T + b_qkv[o], o in [0,768)
    gemm_bt<<<dim3(6, 128), 256, 0, stream>>>(xn, wq, nullptr, b_qkv, nullptr, qkb, 0, 768);
    // V^T fp8: C[d][tok] = w_v @ xn^T + b_qkv[768+d]
    gemm_bt<<<dim3(128, 3), 256, 0, stream>>>(wq + (size_t)768 * 384, xn,
                                              b_qkv + 768, nullptr, nullptr, vtb, 1, 16384);
    flash_kernel<<<dim3(64, 8), 256, 0, stream>>>(qkb, vtb, xn, ob, mlb);
    merge_kernel<<<4096, 256, 0, stream>>>(xn, ob, mlb, ob);
    // proj (transposed output) + bias + residual, fp32 out
    gemm_bt<<<dim3(128, 3), 256, 0, stream>>>(wp, ob, b_proj, nullptr, x, out, 2, 0);
}

// Round 6
// 288.619 us; speedup vs baseline: 1.2229x; 1.2229x over previous
//
#include <hip/hip_runtime.h>
#include <cstdint>
#include <cstddef>

typedef __bf16 bf16;
typedef __bf16 bf16x8 __attribute__((ext_vector_type(8)));
typedef float  f32x4 __attribute__((ext_vector_type(4)));
typedef float  f32x16 __attribute__((ext_vector_type(16)));
typedef int    i32x4 __attribute__((ext_vector_type(4)));
typedef int    i32x8 __attribute__((ext_vector_type(8)));

#define MFMA16(a, b, c) __builtin_amdgcn_mfma_f32_16x16x32_bf16((a), (b), (c), 0, 0, 0)
// MX-scaled fp8 MFMA, both scales = 1.0 (E8M0 127): fmt a=b=0 (fp8 e4m3)
#define MFMA_MX(a, b, c) \
    __builtin_amdgcn_mfma_scale_f32_32x32x64_f8f6f4((a), (b), (c), 0, 0, 0, 0x7F, 0, 0x7F)

// float -> fp8 e4m3 (OCP), RNE, single byte
__device__ __forceinline__ uint8_t to_fp8(float v) {
    return (uint8_t)(__builtin_amdgcn_cvt_pk_fp8_f32(v, v, 0, false) & 0xff);
}

// 32B load as two 16B vector loads (works for LDS: 2x ds_read_b128)
__device__ __forceinline__ i32x8 ld32(const void* p) {
    i32x4 a = *(const i32x4*)p;
    i32x4 b = *(const i32x4*)((const char*)p + 16);
    i32x8 r;
    r[0] = a[0]; r[1] = a[1]; r[2] = a[2]; r[3] = a[3];
    r[4] = b[0]; r[5] = b[1]; r[6] = b[2]; r[7] = b[3];
    return r;
}

// async global->LDS, 16B per lane. LDS dest is wave-uniform base + lane*16.
__device__ __forceinline__ void gload16(const void* g, void* l) {
    __builtin_amdgcn_global_load_lds(
        (const __attribute__((address_space(1))) unsigned int*)g,
        (__attribute__((address_space(3))) unsigned int*)l,
        16, 0, 0);
}

// ---------------------------------------------------------------------------
// Weight fp32 -> bf16 convert (w_qkv 1152x384, w_proj 384x384)
// ---------------------------------------------------------------------------
__global__ __launch_bounds__(256) void convert_w(
    const float* __restrict__ wqkv, const float* __restrict__ wproj,
    bf16* __restrict__ wq, bf16* __restrict__ wp)
{
    int t = blockIdx.x * 256 + threadIdx.x;      // grid covers 589824
    if (t < 1152 * 384) wq[t] = (bf16)wqkv[t];
    else                wp[t - 1152 * 384] = (bf16)wproj[t - 1152 * 384];
}

// ---------------------------------------------------------------------------
// RMSNorm over channel dim, x [4][384][4096] fp32 -> xn [16384][384] bf16
// ---------------------------------------------------------------------------
__global__ __launch_bounds__(64) void norm_kernel(
    const float* __restrict__ x, const float* __restrict__ gamma,
    bf16* __restrict__ xn)
{
    __shared__ float sG[384];
    int tid = threadIdx.x;
    for (int i = tid; i < 384; i += 64) sG[i] = gamma[i];
    __syncthreads();
    int t = blockIdx.x * 64 + tid;               // 0..16383 (one pixel)
    int b = t >> 12, p = t & 4095;
    const float* xb = x + (size_t)(b * 384) * 4096 + p;
    float ss = 0.f;
    for (int c = 0; c < 384; ++c) { float v = xb[(size_t)c * 4096]; ss += v * v; }
    float scale = 19.595917942265423f / fmaxf(sqrtf(ss), 1e-12f); // sqrt(384)/max(l2,eps)
    bf16* o = xn + (size_t)t * 384;
    for (int c0 = 0; c0 < 384; c0 += 8) {
        bf16x8 v8;
#pragma unroll
        for (int j = 0; j < 8; ++j)
            v8[j] = (bf16)(xb[(size_t)(c0 + j) * 4096] * scale * sG[c0 + j]);
        *(bf16x8*)(o + c0) = v8;
    }
}

// ---------------------------------------------------------------------------
// Generic BT GEMM: C[m][n] = sum_k A[m][k]*B[n][k], K=384 fixed, tiles 128x128.
// mode 0: C fp8 = acc + bias_n[n],  ldc given        (QK -> qkb buffer)
// mode 1: C fp8 = acc + bias_m[m],  ldc given        (V^T buffer)
// mode 2: C fp32 out[(b*384+m)*4096+p] = acc + bias_m[m] + resid[idx], n=b*4096+p
// ---------------------------------------------------------------------------
__global__ __launch_bounds__(256) void gemm_bt(
    const bf16* __restrict__ A, const bf16* __restrict__ B,
    const float* __restrict__ bias_m, const float* __restrict__ bias_n,
    const float* __restrict__ resid, void* __restrict__ Cout,
    int mode, int ldc)
{
    __shared__ bf16 sA[128 * 72];   // 144B rows (128B data + 16B pad)
    __shared__ bf16 sB[128 * 72];
    const int tid = threadIdx.x;
    const int l = tid & 63, w = tid >> 6;
    const int lo = l & 15, hi = l >> 4;
    const int wm = w >> 1, wn = w & 1;
    const int m0 = blockIdx.y * 128, n0 = blockIdx.x * 128;

    f32x4 acc[4][4] = {};

    for (int kt = 0; kt < 6; ++kt) {
        __syncthreads();
        const int k0 = kt * 64;
#pragma unroll
        for (int i = 0; i < 5; ++i) {
            int ci = i * 256 + tid;              // 1152 chunks of 16B per tile
            if (ci < 1152) {
                int row = ci / 9, off = ci % 9;  // off==8 loads harmless slack into pad
                gload16(A + (size_t)(m0 + row) * 384 + k0 + off * 8, (char*)sA + ci * 16);
                gload16(B + (size_t)(n0 + row) * 384 + k0 + off * 8, (char*)sB + ci * 16);
            }
        }
        __syncthreads();
#pragma unroll
        for (int ks = 0; ks < 2; ++ks) {
            bf16x8 af[4], bfr[4];
#pragma unroll
            for (int t = 0; t < 4; ++t)
                af[t] = *(const bf16x8*)(sA + (wm * 64 + t * 16 + lo) * 72 + ks * 32 + hi * 8);
#pragma unroll
            for (int t = 0; t < 4; ++t)
                bfr[t] = *(const bf16x8*)(sB + (wn * 64 + t * 16 + lo) * 72 + ks * 32 + hi * 8);
#pragma unroll
            for (int rt = 0; rt < 4; ++rt)
#pragma unroll
                for (int ct = 0; ct < 4; ++ct)
                    acc[rt][ct] = MFMA16(af[rt], bfr[ct], acc[rt][ct]);
        }
    }

    // epilogue: C/D layout col = lo, row = hi*4 + reg
#pragma unroll
    for (int rt = 0; rt < 4; ++rt) {
#pragma unroll
        for (int ct = 0; ct < 4; ++ct) {
            int mb = m0 + wm * 64 + rt * 16 + hi * 4;
            int n  = n0 + wn * 64 + ct * 16 + lo;
            if (mode == 0) {
                uint8_t* C = (uint8_t*)Cout;
                float bn = bias_n[n];
#pragma unroll
                for (int r = 0; r < 4; ++r)
                    C[(size_t)(mb + r) * ldc + n] = to_fp8(acc[rt][ct][r] + bn);
            } else if (mode == 1) {
                uint8_t* C = (uint8_t*)Cout;
#pragma unroll
                for (int r = 0; r < 4; ++r)
                    C[(size_t)(mb + r) * ldc + n] = to_fp8(acc[rt][ct][r] + bias_m[mb + r]);
            } else {
                float* O = (float*)Cout;
                int bb = n >> 12, p = n & 4095;
#pragma unroll
                for (int r = 0; r < 4; ++r) {
                    int m = mb + r;
                    size_t idx = ((size_t)(bb * 384 + m)) * 4096 + p;
                    O[idx] = acc[rt][ct][r] + bias_m[m] + resid[idx];
                }
            }
        }
    }
}

// ---------------------------------------------------------------------------
// Flash attention, transposed-S, MX-fp8 32x32x64 scaled MFMA (scale=1.0),
// Bk=64, single-buffered LDS (2 blocks/CU), 2 barriers per 64-kv iter.
// qk [16384][768] fp8 (Q|K), vt [384][16384] fp8 (V^T).
// Grid (64 qtiles, b*2+half). Block 256 = 4 waves (wq = q-half, wd = d-half).
// Lane (l31 = q or row, hi2 = k-half). A-frags are 32B/lane -> 2x ds_read_b128,
// conflict-free at pitches 400B (K) and 80B (V^T). S^T[64kv][32q] per wave,
// per-lane online softmax (raw-score domain), P^T -> PV B-frag via 8 shfl,
// O^T[192d][32q] += V^T·P^T with one K=64 MFMA per 32-d tile.
// Partials (unnormalized O bf16 + m*SC,l) merged by merge_kernel.
// ---------------------------------------------------------------------------
__device__ __forceinline__ void stage_tiles64(
    const uint8_t* __restrict__ qk, const uint8_t* __restrict__ vt,
    int kv0, uint8_t* sK, uint8_t* sV, int tid)
{
    const uint8_t* kb = qk + (size_t)kv0 * 768 + 384;
#pragma unroll
    for (int i = 0; i < 7; ++i) {
        int ci = i * 256 + tid;
        if (ci < 1600) {                       // 64 rows * 25 chunks (24 data + 1 pad)
            int row = ci / 25, off = ci % 25;
            gload16(kb + (size_t)row * 768 + off * 16, sK + ci * 16);
        }
    }
    const uint8_t* vb = vt + kv0;
#pragma unroll
    for (int i = 0; i < 8; ++i) {
        int ci = i * 256 + tid;
        if (ci < 1920) {                       // 384 rows * 5 chunks (4 data + 1 pad)
            int row = ci / 5, off = ci % 5;
            gload16(vb + (size_t)row * 16384 + off * 16, sV + ci * 16);
        }
    }
}

__global__ __launch_bounds__(256, 2) void flash_kernel(
    const uint8_t* __restrict__ qk, const uint8_t* __restrict__ vt,
    bf16* __restrict__ op0, bf16* __restrict__ op1, float* __restrict__ ml)
{
    __shared__ char smem[56320];               // K [64][400]=25600 + V^T [384][80]=30720
    uint8_t* sK = (uint8_t*)smem;
    uint8_t* sV = (uint8_t*)smem + 25600;
    const int tid = threadIdx.x;
    const int l = tid & 63, w = tid >> 6;
    const int l31 = l & 31, hi2 = l >> 5;
    const int wq = w >> 1, wd = w & 1;
    const int qt = blockIdx.x, bh = blockIdx.y;
    const int b = bh >> 1, half = bh & 1;
    const int q0 = b * 4096 + qt * 64;
    const int kvbase = b * 4096 + half * 2048;
    const float SC = 0.07362217057594547f;     // (1/sqrt(384)) * log2(e)

    // Q B-frags: lane (l31=q, hi2) holds Q[q0+wq*32+l31][ksw*64 + hi2*32 + j]
    i32x8 qf[6];
    {
        const uint8_t* qrow = qk + (size_t)(q0 + wq * 32 + l31) * 768 + hi2 * 32;
#pragma unroll
        for (int ksw = 0; ksw < 6; ++ksw)
            qf[ksw] = ld32(qrow + ksw * 64);
    }

    f32x16 o[6] = {};    // o[dt]: q=l31, d = wd*192+dt*32+(r&3)+8*(r>>2)+4*hi2
    float m = -1e30f, lsum = 0.f;              // raw-score domain

    for (int kt = 0; kt < 32; ++kt) {
        stage_tiles64(qk, vt, kvbase + kt * 64, sK, sV, tid);
        __syncthreads();                       // DMA drained, tiles ready

        // S^T[64kv][32q] as two 32x32 tiles (kvt): A = K rows, B = Q regs
        f32x16 s0 = {}, s1 = {};
#pragma unroll
        for (int ksw = 0; ksw < 6; ++ksw) {
            i32x8 ak0 = ld32(sK + (size_t)l31 * 400 + ksw * 64 + hi2 * 32);
            i32x8 ak1 = ld32(sK + (size_t)(32 + l31) * 400 + ksw * 64 + hi2 * 32);
            s0 = MFMA_MX(ak0, qf[ksw], s0);
            s1 = MFMA_MX(ak1, qf[ksw], s1);
        }

        // online softmax: lane holds 32 kv (own hi2 blocks) for q=l31
        float mx = s0[0];
#pragma unroll
        for (int r = 1; r < 16; ++r) mx = fmaxf(mx, s0[r]);
#pragma unroll
        for (int r = 0; r < 16; ++r) mx = fmaxf(mx, s1[r]);
        mx = fmaxf(mx, __shfl_xor(mx, 32));
        if (__any(mx > m)) {                   // rare after warmup
            float mn = fmaxf(m, mx);
            float alpha = exp2f((m - mn) * SC);
            m = mn;
            lsum *= alpha;
#pragma unroll
            for (int dt = 0; dt < 6; ++dt)
#pragma unroll
                for (int r = 0; r < 16; ++r) o[dt][r] *= alpha;
        }
        float p0[16], p1[16];
        float rs = 0.f;
        float msc = m * SC;
#pragma unroll
        for (int r = 0; r < 16; ++r) { p0[r] = exp2f(fmaf(s0[r], SC, -msc)); rs += p0[r]; }
#pragma unroll
        for (int r = 0; r < 16; ++r) { p1[r] = exp2f(fmaf(s1[r], SC, -msc)); rs += p1[r]; }
        rs += __shfl_xor(rs, 32);
        lsum += rs;

        // pack P to fp8 dwords. s-reg r of kvt holds kv = kvt*32+(r&3)+8*(r>>2)+4*hi2.
        // own pk dword i = kv {kvt*32 + 8i + 4*hi2 .. +3}. B-frag (this lane) needs
        // kv {hi2*32 + j}: kvt = hi2, interleave own/partner(xor32) dwords.
        int pk0[4], pk1[4];
#pragma unroll
        for (int i = 0; i < 4; ++i) {
            int d = __builtin_amdgcn_cvt_pk_fp8_f32(p0[4 * i], p0[4 * i + 1], 0, false);
            pk0[i] = __builtin_amdgcn_cvt_pk_fp8_f32(p0[4 * i + 2], p0[4 * i + 3], d, true);
            d = __builtin_amdgcn_cvt_pk_fp8_f32(p1[4 * i], p1[4 * i + 1], 0, false);
            pk1[i] = __builtin_amdgcn_cvt_pk_fp8_f32(p1[4 * i + 2], p1[4 * i + 3], d, true);
        }
        i32x8 pf;
#pragma unroll
        for (int i = 0; i < 4; ++i) {
            int x0 = __shfl_xor(pk0[i], 32);   // partner's kvt=0 dword
            int x1 = __shfl_xor(pk1[i], 32);   // partner's kvt=1 dword
            int own = hi2 ? pk1[i] : pk0[i];
            int oth = hi2 ? x1 : x0;
            pf[2 * i]     = hi2 ? oth : own;   // kv 8i+0..3 (rel. to hi2*32)
            pf[2 * i + 1] = hi2 ? own : oth;   // kv 8i+4..7
        }

        // O^T[d][q] += V^T · P^T  (A: V^T rows m=d, k = kv = hi2*32+j, K=64)
#pragma unroll
        for (int dt = 0; dt < 6; ++dt) {
            i32x8 av = ld32(sV + (size_t)(wd * 192 + dt * 32 + l31) * 80 + hi2 * 32);
            o[dt] = MFMA_MX(av, pf, o[dt]);
        }

        __syncthreads();                       // all reads done before next stage
    }

    // epilogue: per-wave O^T -> O transpose through LDS (reuse tile space)
    float* tr = (float*)(smem + w * 4608);     // [32 q][36 pitch] fp32
    bf16* dst = half ? op1 : op0;
#pragma unroll
    for (int dt = 0; dt < 6; ++dt) {
#pragma unroll
        for (int r = 0; r < 16; ++r) {
            int d32 = (r & 3) + 8 * (r >> 2) + 4 * hi2;
            tr[l31 * 36 + d32] = o[dt][r];
        }
        f32x4 v0 = *(f32x4*)(tr + l31 * 36 + hi2 * 16 + 0);
        f32x4 v1 = *(f32x4*)(tr + l31 * 36 + hi2 * 16 + 4);
        f32x4 v2 = *(f32x4*)(tr + l31 * 36 + hi2 * 16 + 8);
        f32x4 v3 = *(f32x4*)(tr + l31 * 36 + hi2 * 16 + 12);
        bf16x8 h0, h1;
#pragma unroll
        for (int j = 0; j < 4; ++j) {
            h0[j] = (bf16)v0[j]; h0[4 + j] = (bf16)v1[j];
            h1[j] = (bf16)v2[j]; h1[4 + j] = (bf16)v3[j];
        }
        size_t tok = (size_t)(q0 + wq * 32 + l31);
        bf16* drow = dst + tok * 384 + wd * 192 + dt * 32 + hi2 * 16;
        *(bf16x8*)(drow + 0) = h0;
        *(bf16x8*)(drow + 8) = h1;
        __syncthreads();                       // keep waves in step (cheap)
    }
    if (wd == 0 && hi2 == 0) {
        int tok = q0 + wq * 32 + l31;
        ml[(size_t)(half * 16384 + tok) * 2 + 0] = m * SC;   // scaled domain
        ml[(size_t)(half * 16384 + tok) * 2 + 1] = lsum;
    }
}

// ---------------------------------------------------------------------------
// Merge the two kv-half partials: out = (a0*O0 + a1*O1) / (a0*l0 + a1*l1).
// One wave per token; p1 aliases ob (in-place safe, element-wise).
// ---------------------------------------------------------------------------
__global__ __launch_bounds__(256) void merge_kernel(
    const bf16* __restrict__ p0, const bf16* __restrict__ p1,
    const float* __restrict__ ml, bf16* __restrict__ ob)
{
    int tok = blockIdx.x * 4 + (threadIdx.x >> 6);
    int l = threadIdx.x & 63;
    float m0 = ml[(size_t)tok * 2 + 0], l0 = ml[(size_t)tok * 2 + 1];
    float m1 = ml[(size_t)(16384 + tok) * 2 + 0], l1 = ml[(size_t)(16384 + tok) * 2 + 1];
    float mM = fmaxf(m0, m1);
    float a0 = exp2f(m0 - mM), a1 = exp2f(m1 - mM);
    float inv = 1.0f / (a0 * l0 + a1 * l1);
    float w0 = a0 * inv, w1 = a1 * inv;
    if (l < 48) {
        size_t off = (size_t)tok * 384 + l * 8;
        bf16x8 v0 = *(const bf16x8*)(p0 + off);
        bf16x8 v1 = *(const bf16x8*)(p1 + off);
        bf16x8 r;
#pragma unroll
        for (int j = 0; j < 8; ++j)
            r[j] = (bf16)((float)v0[j] * w0 + (float)v1[j] * w1);
        *(bf16x8*)(ob + off) = r;
    }
}

// ---------------------------------------------------------------------------
extern "C" void kernel_launch(void* const* d_in, const int* in_sizes, int n_in,
                              void* d_out, int out_size, void* d_ws, size_t ws_size,
                              hipStream_t stream) {
    const float* x      = (const float*)d_in[0];
    const float* gamma  = (const float*)d_in[1];
    const float* w_qkv  = (const float*)d_in[2];
    const float* b_qkv  = (const float*)d_in[3];
    const float* w_proj = (const float*)d_in[4];
    const float* b_proj = (const float*)d_in[5];
    float* out = (float*)d_out;

    // workspace carve (~46 MiB); staging 16B overreads at buffer tails land
    // in the next ws buffer. xn is dead after the two gemms -> reused as op0.
    char* ws = (char*)d_ws;
    bf16* xn  = (bf16*)ws;    ws += (size_t)16384 * 384 * 2;   // normalized x / flash partial-0
    uint8_t* qkb = (uint8_t*)ws; ws += (size_t)16384 * 768;    // Q|K fp8, [tok][768]
    uint8_t* vtb = (uint8_t*)ws; ws += (size_t)384 * 16384;    // V^T fp8, [d][tok]
    bf16* ob  = (bf16*)ws;    ws += (size_t)16384 * 384 * 2;   // flash partial-1 / merged attn out
    bf16* wq  = (bf16*)ws;    ws += (size_t)1152 * 384 * 2;    // w_qkv bf16
    bf16* wp  = (bf16*)ws;    ws += (size_t)384 * 384 * 2;     // w_proj bf16
    float* mlb = (float*)ws;  ws += (size_t)2 * 16384 * 2 * 4; // m*SC,l per (half, tok)

    convert_w<<<2304, 256, 0, stream>>>(w_qkv, w_proj, wq, wp);
    norm_kernel<<<256, 64, 0, stream>>>(x, gamma, xn);
    // QK fp8: C[tok][o] = xn @ w_qk^T + b_qkv[o], o in [0,768)
    gemm_bt<<<dim3(6, 128), 256, 0, stream>>>(xn, wq, nullptr, b_qkv, nullptr, qkb, 0, 768);
    // V^T fp8: C[d][tok] = w_v @ xn^T + b_qkv[768+d]
    gemm_bt<<<dim3(128, 3), 256, 0, stream>>>(wq + (size_t)768 * 384, xn,
                                              b_qkv + 768, nullptr, nullptr, vtb, 1, 16384);
    flash_kernel<<<dim3(64, 8), 256, 0, stream>>>(qkb, vtb, xn, ob, mlb);
    merge_kernel<<<4096, 256, 0, stream>>>(xn, ob, mlb, ob);
    // proj (transposed output) + bias + residual, fp32 out
    gemm_bt<<<dim3(128, 3), 256, 0, stream>>>(wp, ob, b_proj, nullptr, x, out, 2, 0);
}